// Round 1
// baseline (587.518 us; speedup 1.0000x reference)
//
#include <hip/hip_runtime.h>

// SnConv3: B=8, N=32, C=64, O=64
#define NBATCH 8
#define NN 32
#define NC 64
#define NO 64
#define C6 384
#define C10 640
#define C12 768
#define C5 320

// workspace layout (float offsets)
static constexpr int OFF_A2  = 0;        // [8][32][32][384]  = 3,145,728
static constexpr int OFF_A1  = 3145728;  // [8][32][640]      =   163,840
static constexpr int OFF_A0  = 3309568;  // [8][320]          =     2,560
static constexpr int OFF_SL  = 3312128;  // [3][8][32][32][64]= 1,572,864
static constexpr int OFF_R1  = 4884992;  // [3][8][32][64]    =    49,152
static constexpr int OFF_R1T = 4934144;  // [3][8][32][64]    =    49,152
static constexpr int OFF_R0  = 4983296;  // [3][8][64]        =     1,536
static constexpr int OFF_MD  = 4984832;  // [8][32][64]       =    16,384
// total 5,001,216 floats = ~20 MB

// ---------------------------------------------------------------------------
// K1: a2 chunks: s1,s2,s3 (means over one axis) + d12,d13,d23 (diagonals)
// one thread per (b,u,v,c); 524288 threads
// ---------------------------------------------------------------------------
__global__ __launch_bounds__(256) void k_contract2(const float* __restrict__ x,
                                                   float* __restrict__ ws) {
    int id = blockIdx.x * 256 + threadIdx.x;
    int c = id & 63;
    int v = (id >> 6) & 31;
    int u = (id >> 11) & 31;
    int b = id >> 16;
    const float inv = 1.0f / 32.0f;
    const float* xb = x + (size_t)b * 2097152;  // 32*32*32*64

    float s1 = 0.f, s2 = 0.f, s3 = 0.f;
    {   // s1[b,u,v,c] = mean_i x[b,i,u,v,c]
        const float* p = xb + u * 2048 + v * 64 + c;
        for (int i = 0; i < 32; ++i) s1 += p[i * 65536];
    }
    {   // s2[b,u,v,c] = mean_j x[b,u,j,v,c]
        const float* p = xb + u * 65536 + v * 64 + c;
        for (int j = 0; j < 32; ++j) s2 += p[j * 2048];
    }
    {   // s3[b,u,v,c] = mean_k x[b,u,v,k,c]
        const float* p = xb + u * 65536 + v * 2048 + c;
        for (int k = 0; k < 32; ++k) s3 += p[k * 64];
    }
    float d12 = xb[v * 65536 + v * 2048 + u * 64 + c];  // x[b,v,v,u,c]
    float d13 = xb[v * 65536 + u * 2048 + v * 64 + c];  // x[b,v,u,v,c]
    float d23 = xb[u * 65536 + v * 2048 + v * 64 + c];  // x[b,u,v,v,c]

    float* a2 = ws + OFF_A2 + ((size_t)(b * 32 + u) * 32 + v) * C6;
    a2[0 * 64 + c] = s1 * inv;
    a2[1 * 64 + c] = s2 * inv;
    a2[2 * 64 + c] = s3 * inv;
    a2[3 * 64 + c] = d12;
    a2[4 * 64 + c] = d13;
    a2[5 * 64 + c] = d23;
}

// ---------------------------------------------------------------------------
// K2: a1 (10 chunks of C) from a2 + triple diagonal.  one thread per (b,t,c)
// ---------------------------------------------------------------------------
__global__ __launch_bounds__(256) void k_contract1(const float* __restrict__ x,
                                                   float* __restrict__ ws) {
    int id = blockIdx.x * 256 + threadIdx.x;  // 16384
    int c = id & 63;
    int t = (id >> 6) & 31;
    int b = id >> 11;
    const float* a2 = ws + OFF_A2 + (size_t)b * 32 * 32 * C6;

    float su0 = 0, su3 = 0, su4 = 0, su5 = 0;      // mean over first spatial idx
    float sv0 = 0, sv1 = 0, sv3 = 0, sv4 = 0, sv5 = 0;  // mean over second
    for (int u = 0; u < 32; ++u) {
        const float* row = a2 + (u * 32 + t) * C6;
        su0 += row[0 * 64 + c];
        su3 += row[3 * 64 + c];
        su4 += row[4 * 64 + c];
        su5 += row[5 * 64 + c];
    }
    for (int v = 0; v < 32; ++v) {
        const float* row = a2 + (t * 32 + v) * C6;
        sv0 += row[0 * 64 + c];
        sv1 += row[1 * 64 + c];
        sv3 += row[3 * 64 + c];
        sv4 += row[4 * 64 + c];
        sv5 += row[5 * 64 + c];
    }
    float td = x[(((size_t)b * 32 + t) * 32 + t) * 2048 + t * 64 + c];  // x[b,t,t,t,c]

    float* a1 = ws + OFF_A1 + ((size_t)b * 32 + t) * C10;
    const float inv = 1.0f / 32.0f;
    a1[0 * 64 + c] = su0 * inv;  // x.mean((1,2))
    a1[1 * 64 + c] = sv0 * inv;  // x.mean((1,3))
    a1[2 * 64 + c] = sv1 * inv;  // x.mean((2,3))
    a1[3 * 64 + c] = su3 * inv;  // d12.mean(1)
    a1[4 * 64 + c] = sv3 * inv;  // d12.mean(2)
    a1[5 * 64 + c] = su4 * inv;  // d13.mean(1)
    a1[6 * 64 + c] = sv4 * inv;  // d13.mean(2)
    a1[7 * 64 + c] = su5 * inv;  // d23.mean(1)
    a1[8 * 64 + c] = sv5 * inv;  // d23.mean(2)
    a1[9 * 64 + c] = td;         // tdiag
}

// ---------------------------------------------------------------------------
// K3: a0 (5 chunks of C) from a1.  one thread per (b,c): 512 threads
// ---------------------------------------------------------------------------
__global__ __launch_bounds__(256) void k_contract0(float* __restrict__ ws) {
    int id = blockIdx.x * 256 + threadIdx.x;
    if (id >= 512) return;
    int c = id & 63;
    int b = id >> 6;
    const float* a1 = ws + OFF_A1 + (size_t)b * 32 * C10;
    float s0 = 0, s1 = 0, s2 = 0, s3 = 0, s4 = 0;
    for (int t = 0; t < 32; ++t) {
        const float* row = a1 + t * C10;
        s0 += row[0 * 64 + c];
        s1 += row[3 * 64 + c];
        s2 += row[5 * 64 + c];
        s3 += row[7 * 64 + c];
        s4 += row[9 * 64 + c];
    }
    float* a0 = ws + OFF_A0 + b * C5;
    const float inv = 1.0f / 32.0f;
    a0[0 * 64 + c] = s0 * inv;
    a0[1 * 64 + c] = s1 * inv;
    a0[2 * 64 + c] = s2 * inv;
    a0[3 * 64 + c] = s3 * inv;
    a0[4 * 64 + c] = s4 * inv;
}

// ---------------------------------------------------------------------------
// K4: small row GEMMs: r1 = a1@W12+b12, r1t = a1@W12t+b12t,
//     mdiag = a1@W11+b11 + a0@W01+b01, r0 = a0@W02+b02
// flat id over 49152 + 49152 + 16384 + 1536 = 116224
// ---------------------------------------------------------------------------
__global__ __launch_bounds__(256) void k_rowmix(
    const float* __restrict__ W12, const float* __restrict__ b12,
    const float* __restrict__ W12t, const float* __restrict__ b12t,
    const float* __restrict__ W02, const float* __restrict__ b02,
    const float* __restrict__ W11, const float* __restrict__ b11,
    const float* __restrict__ W01, const float* __restrict__ b01,
    float* __restrict__ ws) {
    int id = blockIdx.x * 256 + threadIdx.x;
    if (id < 98304) {  // r1 / r1t
        bool second = id >= 49152;
        int q = second ? id - 49152 : id;
        int o = q & 63;
        int t = (q >> 6) & 31;
        int b = (q >> 11) & 7;
        int i = q >> 14;
        const float* W = (second ? W12t : W12) + (size_t)i * C10 * NO;
        const float* bb = (second ? b12t : b12) + i * NO;
        const float* a1 = ws + OFF_A1 + ((size_t)b * 32 + t) * C10;
        float acc = bb[o];
        for (int m = 0; m < C10; ++m) acc += a1[m] * W[m * NO + o];
        ws[(second ? OFF_R1T : OFF_R1) + (((size_t)i * 8 + b) * 32 + t) * NO + o] = acc;
    } else if (id < 114688) {  // mdiag
        int q = id - 98304;
        int o = q & 63;
        int t = (q >> 6) & 31;
        int b = q >> 11;
        const float* a1 = ws + OFF_A1 + ((size_t)b * 32 + t) * C10;
        const float* a0 = ws + OFF_A0 + (size_t)b * C5;
        float acc = b11[o] + b01[o];
        for (int m = 0; m < C10; ++m) acc += a1[m] * W11[m * NO + o];
        for (int m = 0; m < C5; ++m) acc += a0[m] * W01[m * NO + o];
        ws[OFF_MD + ((size_t)b * 32 + t) * NO + o] = acc;
    } else if (id < 116224) {  // r0
        int q = id - 114688;
        int o = q & 63;
        int b = (q >> 6) & 7;
        int i = q >> 9;
        const float* a0 = ws + OFF_A0 + (size_t)b * C5;
        float acc = b02[i * NO + o];
        for (int m = 0; m < C5; ++m) acc += a0[m] * W02[(size_t)i * C5 * NO + m * NO + o];
        ws[OFF_R0 + ((size_t)i * 8 + b) * NO + o] = acc;
    }
}

// ---------------------------------------------------------------------------
// K5: slices[i][b,t,d,o] = [a2[b,t,d,:] ‖ a2[b,d,t,:]] @ W22[i] + b22[i]
//                          + r1[i][b,t,o] + r1t[i][b,d,o] + r0[i][b,o]
// block per (i,b,t): 768 blocks, 256 threads, two-phase LDS (48 KiB)
// ---------------------------------------------------------------------------
__global__ __launch_bounds__(256) void k_slices(const float* __restrict__ W22,
                                                const float* __restrict__ b22,
                                                float* __restrict__ ws) {
    __shared__ float4 A4[3072];  // [32 d][96 float4] = 32 x 384 floats
    int blk = blockIdx.x;        // i*256 + b*32 + t
    int i = blk >> 8;
    int b = (blk >> 5) & 7;
    int t = blk & 31;
    int tid = threadIdx.x;
    int o = tid & 63;
    int dgrp = tid >> 6;  // wave id: 8 d's per thread
    const float* Wt = W22 + (size_t)i * C12 * NO;

    // phase 1: A[d][m] = a2[b,t,d,m]  (contiguous 48 KiB)
    {
        const float4* s4 = (const float4*)(ws + OFF_A2 + (size_t)((b * 32 + t) * 32) * C6);
        for (int l = tid; l < 3072; l += 256) A4[l] = s4[l];
    }
    __syncthreads();

    float acc[8];
    {
        float r1 = ws[OFF_R1 + (((size_t)i * 8 + b) * 32 + t) * NO + o];
        float r0 = ws[OFF_R0 + ((size_t)i * 8 + b) * NO + o];
        float bb = b22[i * NO + o];
#pragma unroll
        for (int kk = 0; kk < 8; ++kk) acc[kk] = bb + r1 + r0;
    }
    for (int m4 = 0; m4 < 96; ++m4) {
        float w0 = Wt[(m4 * 4 + 0) * NO + o];
        float w1 = Wt[(m4 * 4 + 1) * NO + o];
        float w2 = Wt[(m4 * 4 + 2) * NO + o];
        float w3 = Wt[(m4 * 4 + 3) * NO + o];
#pragma unroll
        for (int kk = 0; kk < 8; ++kk) {
            float4 a = A4[(dgrp * 8 + kk) * 96 + m4];  // wave-uniform: LDS broadcast
            acc[kk] += a.x * w0 + a.y * w1 + a.z * w2 + a.w * w3;
        }
    }
    __syncthreads();

    // phase 2: A[d][m] = a2[b,d,t,m]  (strided rows)
    for (int l = tid; l < 3072; l += 256) {
        int f = l * 4;
        int d = f / C6;
        int m = f - d * C6;
        A4[l] = *(const float4*)(ws + OFF_A2 + (size_t)((b * 32 + d) * 32 + t) * C6 + m);
    }
    __syncthreads();
    for (int m4 = 0; m4 < 96; ++m4) {
        float w0 = Wt[(C6 + m4 * 4 + 0) * NO + o];
        float w1 = Wt[(C6 + m4 * 4 + 1) * NO + o];
        float w2 = Wt[(C6 + m4 * 4 + 2) * NO + o];
        float w3 = Wt[(C6 + m4 * 4 + 3) * NO + o];
#pragma unroll
        for (int kk = 0; kk < 8; ++kk) {
            float4 a = A4[(dgrp * 8 + kk) * 96 + m4];
            acc[kk] += a.x * w0 + a.y * w1 + a.z * w2 + a.w * w3;
        }
    }
#pragma unroll
    for (int kk = 0; kk < 8; ++kk) {
        int d = dgrp * 8 + kk;
        float v = acc[kk] + ws[OFF_R1T + (((size_t)i * 8 + b) * 32 + d) * NO + o];
        ws[OFF_SL + ((((size_t)i * 8 + b) * 32 + t) * 32 + d) * NO + o] = v;
    }
}

// ---------------------------------------------------------------------------
// K6 (main): T[b,i,j,k,o] = b33[o] + sum_p sum_c x[b,perm_p(i,j,k),c]*W33[p*C+c,o]
// block per (b,i,j): 8192 blocks; LDS-stage 32k x 384 A-tile; thread = (kgrp,o)
// ---------------------------------------------------------------------------
__global__ __launch_bounds__(256) void k_main(const float* __restrict__ x,
                                              const float* __restrict__ W33,
                                              const float* __restrict__ b33,
                                              float* __restrict__ T) {
    __shared__ float4 A4[3072];  // [32 k][96 float4]
    int blk = blockIdx.x;  // b*1024 + i*32 + j
    int b = blk >> 10;
    int i = (blk >> 5) & 31;
    int j = blk & 31;
    int tid = threadIdx.x;
    const float* xb = x + (size_t)b * 2097152;

    // stage permuted A-tile: A[k][p*64+c] = x[b, perm_p applied, c]
    for (int l = tid; l < 3072; l += 256) {
        int f = l * 4;
        int k = f / C6;
        int r = f - k * C6;
        int p = r >> 6;
        int c = r & 63;
        int src;
        switch (p) {  // PERMS order (1,2,3),(1,3,2),(2,1,3),(2,3,1),(3,1,2),(3,2,1)
            case 0: src = i * 65536 + j * 2048 + k * 64; break;  // x[b,i,j,k]
            case 1: src = i * 65536 + k * 2048 + j * 64; break;  // x[b,i,k,j]
            case 2: src = j * 65536 + i * 2048 + k * 64; break;  // x[b,j,i,k]
            case 3: src = k * 65536 + i * 2048 + j * 64; break;  // x[b,k,i,j]
            case 4: src = j * 65536 + k * 2048 + i * 64; break;  // x[b,j,k,i]
            default: src = k * 65536 + j * 2048 + i * 64; break; // x[b,k,j,i]
        }
        A4[l] = *(const float4*)(xb + src + c);
    }
    __syncthreads();

    int o = tid & 63;
    int kgrp = tid >> 6;
    float acc[8];
    float bb = b33[o];
#pragma unroll
    for (int kk = 0; kk < 8; ++kk) acc[kk] = bb;

    for (int m4 = 0; m4 < 96; ++m4) {
        float w0 = W33[(m4 * 4 + 0) * NO + o];  // wave-coalesced 256B
        float w1 = W33[(m4 * 4 + 1) * NO + o];
        float w2 = W33[(m4 * 4 + 2) * NO + o];
        float w3 = W33[(m4 * 4 + 3) * NO + o];
#pragma unroll
        for (int kk = 0; kk < 8; ++kk) {
            float4 a = A4[(kgrp * 8 + kk) * 96 + m4];  // wave-uniform: broadcast
            acc[kk] += a.x * w0 + a.y * w1 + a.z * w2 + a.w * w3;
        }
    }
    float* Tb = T + (size_t)blk * 2048;
#pragma unroll
    for (int kk = 0; kk < 8; ++kk) {
        Tb[(kgrp * 8 + kk) * 64 + o] = acc[kk];
    }
}

// ---------------------------------------------------------------------------
// K7: expand — scatter-add slices onto diagonal planes + mdiag on triple diag.
// one thread per (b,t,d,o); index sets disjoint across threads (t==d fused)
// ---------------------------------------------------------------------------
__global__ __launch_bounds__(256) void k_expand(float* __restrict__ T,
                                                const float* __restrict__ ws) {
    int id = blockIdx.x * 256 + threadIdx.x;  // 524288
    int o = id & 63;
    int d = (id >> 6) & 31;
    int t = (id >> 11) & 31;
    int b = id >> 16;
    size_t sb = (((size_t)b * 32 + t) * 32 + d) * 64 + o;
    float s0 = ws[OFF_SL + 0 * 524288 + sb];
    float s1 = ws[OFF_SL + 1 * 524288 + sb];
    float s2 = ws[OFF_SL + 2 * 524288 + sb];
    float* Tb = T + (size_t)b * 2097152;
    if (t != d) {
        Tb[d * 65536 + d * 2048 + t * 64 + o] += s0;  // plane (1,2)
        Tb[d * 65536 + t * 2048 + d * 64 + o] += s1;  // plane (1,3)
        Tb[t * 65536 + d * 2048 + d * 64 + o] += s2;  // plane (2,3)
    } else {
        float md = ws[OFF_MD + ((size_t)b * 32 + d) * 64 + o];
        Tb[d * 65536 + d * 2048 + d * 64 + o] += s0 + s1 + s2 + md;
    }
}

// ---------------------------------------------------------------------------
extern "C" void kernel_launch(void* const* d_in, const int* in_sizes, int n_in,
                              void* d_out, int out_size, void* d_ws, size_t ws_size,
                              hipStream_t stream) {
    const float* x    = (const float*)d_in[0];
    const float* W33  = (const float*)d_in[1];
    const float* b33  = (const float*)d_in[2];
    const float* W22  = (const float*)d_in[3];
    const float* b22  = (const float*)d_in[4];
    const float* W12  = (const float*)d_in[5];
    const float* b12  = (const float*)d_in[6];
    const float* W12t = (const float*)d_in[7];
    const float* b12t = (const float*)d_in[8];
    const float* W02  = (const float*)d_in[9];
    const float* b02  = (const float*)d_in[10];
    const float* W11  = (const float*)d_in[11];
    const float* b11  = (const float*)d_in[12];
    const float* W01  = (const float*)d_in[13];
    const float* b01  = (const float*)d_in[14];
    float* T  = (float*)d_out;
    float* ws = (float*)d_ws;

    hipLaunchKernelGGL(k_contract2, dim3(2048), dim3(256), 0, stream, x, ws);
    hipLaunchKernelGGL(k_contract1, dim3(64), dim3(256), 0, stream, x, ws);
    hipLaunchKernelGGL(k_contract0, dim3(2), dim3(256), 0, stream, ws);
    hipLaunchKernelGGL(k_rowmix, dim3(454), dim3(256), 0, stream,
                       W12, b12, W12t, b12t, W02, b02, W11, b11, W01, b01, ws);
    hipLaunchKernelGGL(k_slices, dim3(768), dim3(256), 0, stream, W22, b22, ws);
    hipLaunchKernelGGL(k_main, dim3(8192), dim3(256), 0, stream, x, W33, b33, T);
    hipLaunchKernelGGL(k_expand, dim3(2048), dim3(256), 0, stream, T, ws);
}

// Round 2
// 350.019 us; speedup vs baseline: 1.6785x; 1.6785x over previous
//
#include <hip/hip_runtime.h>

// SnConv3: B=8, N=32, C=64, O=64
#define NBATCH 8
#define NN 32
#define NC 64
#define NO 64
#define C6 384
#define C10 640
#define C12 768
#define C5 320

typedef __attribute__((ext_vector_type(8))) short short8;   // 8 bf16 (4 VGPRs)
typedef __attribute__((ext_vector_type(4))) float float4v;  // 4 fp32

// workspace layout (float offsets)
static constexpr int OFF_A2  = 0;        // [8][32][32][384]  = 3,145,728
static constexpr int OFF_A1  = 3145728;  // [8][32][640]      =   163,840
static constexpr int OFF_A0  = 3309568;  // [8][320]          =     2,560
static constexpr int OFF_SL  = 3312128;  // [3][8][32][32][64]= 1,572,864
static constexpr int OFF_R1  = 4884992;  // [3][8][32][64]    =    49,152
static constexpr int OFF_R1T = 4934144;  // [3][8][32][64]    =    49,152
static constexpr int OFF_R0  = 4983296;  // [3][8][64]        =     1,536
static constexpr int OFF_MD  = 4984832;  // [8][32][64]       =    16,384
static constexpr int OFF_WB  = 5001216;  // W33 bf16 B-fragments: 24576 shorts = 12,288 floats
// total ~5,013,504 floats = ~20.1 MB

__device__ __forceinline__ unsigned short f2bf(float f) {
    union { float f; unsigned u; } x{f};
    unsigned r = x.u + 0x7fffu + ((x.u >> 16) & 1u);  // RNE
    return (unsigned short)(r >> 16);
}

// ---------------------------------------------------------------------------
// K0: W33 [384][64] f32 -> bf16 B-fragments for mfma_f32_16x16x32_bf16.
// frag(nt,ks): lane l holds B[k=ks*32+(l>>4)*8+j][n=nt*16+(l&15)], j=0..7
// ---------------------------------------------------------------------------
__global__ __launch_bounds__(256) void k_prepw(const float* __restrict__ W33,
                                               float* __restrict__ ws) {
    int id = blockIdx.x * 256 + threadIdx.x;  // 3072
    if (id >= 3072) return;
    int lane = id & 63;
    int ks = (id >> 6) % 12;
    int nt = (id >> 6) / 12;
    int n = nt * 16 + (lane & 15);
    int k0 = ks * 32 + (lane >> 4) * 8;
    unsigned short* WB = (unsigned short*)(ws + OFF_WB);
    unsigned short* dst = WB + (size_t)((nt * 12 + ks) * 64 + lane) * 8;
#pragma unroll
    for (int jj = 0; jj < 8; ++jj) dst[jj] = f2bf(W33[(k0 + jj) * 64 + n]);
}

// ---------------------------------------------------------------------------
// K1: a2 chunks: s1,s2,s3 (means over one axis) + d12,d13,d23 (diagonals)
// ---------------------------------------------------------------------------
__global__ __launch_bounds__(256) void k_contract2(const float* __restrict__ x,
                                                   float* __restrict__ ws) {
    int id = blockIdx.x * 256 + threadIdx.x;
    int c = id & 63;
    int v = (id >> 6) & 31;
    int u = (id >> 11) & 31;
    int b = id >> 16;
    const float inv = 1.0f / 32.0f;
    const float* xb = x + (size_t)b * 2097152;

    float s1 = 0.f, s2 = 0.f, s3 = 0.f;
    {
        const float* p = xb + u * 2048 + v * 64 + c;
        for (int i = 0; i < 32; ++i) s1 += p[i * 65536];
    }
    {
        const float* p = xb + u * 65536 + v * 64 + c;
        for (int j = 0; j < 32; ++j) s2 += p[j * 2048];
    }
    {
        const float* p = xb + u * 65536 + v * 2048 + c;
        for (int k = 0; k < 32; ++k) s3 += p[k * 64];
    }
    float d12 = xb[v * 65536 + v * 2048 + u * 64 + c];
    float d13 = xb[v * 65536 + u * 2048 + v * 64 + c];
    float d23 = xb[u * 65536 + v * 2048 + v * 64 + c];

    float* a2 = ws + OFF_A2 + ((size_t)(b * 32 + u) * 32 + v) * C6;
    a2[0 * 64 + c] = s1 * inv;
    a2[1 * 64 + c] = s2 * inv;
    a2[2 * 64 + c] = s3 * inv;
    a2[3 * 64 + c] = d12;
    a2[4 * 64 + c] = d13;
    a2[5 * 64 + c] = d23;
}

// ---------------------------------------------------------------------------
// K2: a1 (10 chunks of C) from a2 + triple diagonal.
// ---------------------------------------------------------------------------
__global__ __launch_bounds__(256) void k_contract1(const float* __restrict__ x,
                                                   float* __restrict__ ws) {
    int id = blockIdx.x * 256 + threadIdx.x;  // 16384
    int c = id & 63;
    int t = (id >> 6) & 31;
    int b = id >> 11;
    const float* a2 = ws + OFF_A2 + (size_t)b * 32 * 32 * C6;

    float su0 = 0, su3 = 0, su4 = 0, su5 = 0;
    float sv0 = 0, sv1 = 0, sv3 = 0, sv4 = 0, sv5 = 0;
    for (int u = 0; u < 32; ++u) {
        const float* row = a2 + (u * 32 + t) * C6;
        su0 += row[0 * 64 + c];
        su3 += row[3 * 64 + c];
        su4 += row[4 * 64 + c];
        su5 += row[5 * 64 + c];
    }
    for (int v = 0; v < 32; ++v) {
        const float* row = a2 + (t * 32 + v) * C6;
        sv0 += row[0 * 64 + c];
        sv1 += row[1 * 64 + c];
        sv3 += row[3 * 64 + c];
        sv4 += row[4 * 64 + c];
        sv5 += row[5 * 64 + c];
    }
    float td = x[(((size_t)b * 32 + t) * 32 + t) * 2048 + t * 64 + c];

    float* a1 = ws + OFF_A1 + ((size_t)b * 32 + t) * C10;
    const float inv = 1.0f / 32.0f;
    a1[0 * 64 + c] = su0 * inv;
    a1[1 * 64 + c] = sv0 * inv;
    a1[2 * 64 + c] = sv1 * inv;
    a1[3 * 64 + c] = su3 * inv;
    a1[4 * 64 + c] = sv3 * inv;
    a1[5 * 64 + c] = su4 * inv;
    a1[6 * 64 + c] = sv4 * inv;
    a1[7 * 64 + c] = su5 * inv;
    a1[8 * 64 + c] = sv5 * inv;
    a1[9 * 64 + c] = td;
}

// ---------------------------------------------------------------------------
// K3: a0 (5 chunks of C) from a1.
// ---------------------------------------------------------------------------
__global__ __launch_bounds__(256) void k_contract0(float* __restrict__ ws) {
    int id = blockIdx.x * 256 + threadIdx.x;
    if (id >= 512) return;
    int c = id & 63;
    int b = id >> 6;
    const float* a1 = ws + OFF_A1 + (size_t)b * 32 * C10;
    float s0 = 0, s1 = 0, s2 = 0, s3 = 0, s4 = 0;
    for (int t = 0; t < 32; ++t) {
        const float* row = a1 + t * C10;
        s0 += row[0 * 64 + c];
        s1 += row[3 * 64 + c];
        s2 += row[5 * 64 + c];
        s3 += row[7 * 64 + c];
        s4 += row[9 * 64 + c];
    }
    float* a0 = ws + OFF_A0 + b * C5;
    const float inv = 1.0f / 32.0f;
    a0[0 * 64 + c] = s0 * inv;
    a0[1 * 64 + c] = s1 * inv;
    a0[2 * 64 + c] = s2 * inv;
    a0[3 * 64 + c] = s3 * inv;
    a0[4 * 64 + c] = s4 * inv;
}

// ---------------------------------------------------------------------------
// K4: small row GEMMs: r1, r1t, mdiag, r0
// ---------------------------------------------------------------------------
__global__ __launch_bounds__(256) void k_rowmix(
    const float* __restrict__ W12, const float* __restrict__ b12,
    const float* __restrict__ W12t, const float* __restrict__ b12t,
    const float* __restrict__ W02, const float* __restrict__ b02,
    const float* __restrict__ W11, const float* __restrict__ b11,
    const float* __restrict__ W01, const float* __restrict__ b01,
    float* __restrict__ ws) {
    int id = blockIdx.x * 256 + threadIdx.x;
    if (id < 98304) {  // r1 / r1t
        bool second = id >= 49152;
        int q = second ? id - 49152 : id;
        int o = q & 63;
        int t = (q >> 6) & 31;
        int b = (q >> 11) & 7;
        int i = q >> 14;
        const float* W = (second ? W12t : W12) + (size_t)i * C10 * NO;
        const float* bb = (second ? b12t : b12) + i * NO;
        const float* a1 = ws + OFF_A1 + ((size_t)b * 32 + t) * C10;
        float acc = bb[o];
        for (int m = 0; m < C10; ++m) acc += a1[m] * W[m * NO + o];
        ws[(second ? OFF_R1T : OFF_R1) + (((size_t)i * 8 + b) * 32 + t) * NO + o] = acc;
    } else if (id < 114688) {  // mdiag
        int q = id - 98304;
        int o = q & 63;
        int t = (q >> 6) & 31;
        int b = q >> 11;
        const float* a1 = ws + OFF_A1 + ((size_t)b * 32 + t) * C10;
        const float* a0 = ws + OFF_A0 + (size_t)b * C5;
        float acc = b11[o] + b01[o];
        for (int m = 0; m < C10; ++m) acc += a1[m] * W11[m * NO + o];
        for (int m = 0; m < C5; ++m) acc += a0[m] * W01[m * NO + o];
        ws[OFF_MD + ((size_t)b * 32 + t) * NO + o] = acc;
    } else if (id < 116224) {  // r0
        int q = id - 114688;
        int o = q & 63;
        int b = (q >> 6) & 7;
        int i = q >> 9;
        const float* a0 = ws + OFF_A0 + (size_t)b * C5;
        float acc = b02[i * NO + o];
        for (int m = 0; m < C5; ++m) acc += a0[m] * W02[(size_t)i * C5 * NO + m * NO + o];
        ws[OFF_R0 + ((size_t)i * 8 + b) * NO + o] = acc;
    }
}

// ---------------------------------------------------------------------------
// K5: slices[i][b,t,d,o] — f32 two-phase LDS version
// ---------------------------------------------------------------------------
__global__ __launch_bounds__(256) void k_slices(const float* __restrict__ W22,
                                                const float* __restrict__ b22,
                                                float* __restrict__ ws) {
    __shared__ float4 A4[3072];
    int blk = blockIdx.x;  // i*256 + b*32 + t
    int i = blk >> 8;
    int b = (blk >> 5) & 7;
    int t = blk & 31;
    int tid = threadIdx.x;
    int o = tid & 63;
    int dgrp = tid >> 6;
    const float* Wt = W22 + (size_t)i * C12 * NO;

    {
        const float4* s4 = (const float4*)(ws + OFF_A2 + (size_t)((b * 32 + t) * 32) * C6);
        for (int l = tid; l < 3072; l += 256) A4[l] = s4[l];
    }
    __syncthreads();

    float acc[8];
    {
        float r1 = ws[OFF_R1 + (((size_t)i * 8 + b) * 32 + t) * NO + o];
        float r0 = ws[OFF_R0 + ((size_t)i * 8 + b) * NO + o];
        float bb = b22[i * NO + o];
#pragma unroll
        for (int kk = 0; kk < 8; ++kk) acc[kk] = bb + r1 + r0;
    }
    for (int m4 = 0; m4 < 96; ++m4) {
        float w0 = Wt[(m4 * 4 + 0) * NO + o];
        float w1 = Wt[(m4 * 4 + 1) * NO + o];
        float w2 = Wt[(m4 * 4 + 2) * NO + o];
        float w3 = Wt[(m4 * 4 + 3) * NO + o];
#pragma unroll
        for (int kk = 0; kk < 8; ++kk) {
            float4 a = A4[(dgrp * 8 + kk) * 96 + m4];
            acc[kk] += a.x * w0 + a.y * w1 + a.z * w2 + a.w * w3;
        }
    }
    __syncthreads();

    for (int l = tid; l < 3072; l += 256) {
        int f = l * 4;
        int d = f / C6;
        int m = f - d * C6;
        A4[l] = *(const float4*)(ws + OFF_A2 + (size_t)((b * 32 + d) * 32 + t) * C6 + m);
    }
    __syncthreads();
    for (int m4 = 0; m4 < 96; ++m4) {
        float w0 = Wt[(C6 + m4 * 4 + 0) * NO + o];
        float w1 = Wt[(C6 + m4 * 4 + 1) * NO + o];
        float w2 = Wt[(C6 + m4 * 4 + 2) * NO + o];
        float w3 = Wt[(C6 + m4 * 4 + 3) * NO + o];
#pragma unroll
        for (int kk = 0; kk < 8; ++kk) {
            float4 a = A4[(dgrp * 8 + kk) * 96 + m4];
            acc[kk] += a.x * w0 + a.y * w1 + a.z * w2 + a.w * w3;
        }
    }
#pragma unroll
    for (int kk = 0; kk < 8; ++kk) {
        int d = dgrp * 8 + kk;
        float v = acc[kk] + ws[OFF_R1T + (((size_t)i * 8 + b) * 32 + d) * NO + o];
        ws[OFF_SL + ((((size_t)i * 8 + b) * 32 + t) * 32 + d) * NO + o] = v;
    }
}

// ---------------------------------------------------------------------------
// K6 (main, MFMA): T[b,i,j,k,o] = b33[o] + sum_p,c x[b,perm_p(i,j,k),c]*W33[p*C+c,o]
// block per (b,i,j); A-tile (32 x 384) staged as bf16 in LDS (rows padded +8);
// B (W33) pre-fragmented bf16 in ws, held in registers (24 frags/wave).
// wave wv: m_tile = wv&1 (rows of 16 k's), n_pair = wv>>1 (2 n-tiles of 16 o's)
// ---------------------------------------------------------------------------
__global__ __launch_bounds__(256) void k_main(const float* __restrict__ x,
                                              const float* __restrict__ ws,
                                              const float* __restrict__ b33,
                                              float* __restrict__ T) {
    __shared__ __align__(16) unsigned short As[32 * 392];  // 392 = 384 + 8 pad
    int blk = blockIdx.x;  // b*1024 + i*32 + j
    int b = blk >> 10;
    int i = (blk >> 5) & 31;
    int j = blk & 31;
    int tid = threadIdx.x;
    const float* xb = x + (size_t)b * 2097152;
    const unsigned short* WB = (const unsigned short*)(ws + OFF_WB);

    int wv = tid >> 6;
    int lane = tid & 63;
    int m_tile = wv & 1;
    int n_pair = wv >> 1;

    // B fragments into registers (L2-resident, coalesced dwordx4)
    short8 bfr[2][12];
#pragma unroll
    for (int np = 0; np < 2; ++np) {
        int nt = n_pair * 2 + np;
#pragma unroll
        for (int ks = 0; ks < 12; ++ks)
            bfr[np][ks] = *(const short8*)(WB + (size_t)((nt * 12 + ks) * 64 + lane) * 8);
    }

    // stage permuted A-tile as bf16
    for (int l = tid; l < 3072; l += 256) {
        int f = l * 4;
        int k = f / C6;
        int r = f - k * C6;
        int p = r >> 6;
        int c = r & 63;
        int src;
        switch (p) {  // PERMS order (1,2,3),(1,3,2),(2,1,3),(2,3,1),(3,1,2),(3,2,1)
            case 0: src = i * 65536 + j * 2048 + k * 64; break;
            case 1: src = i * 65536 + k * 2048 + j * 64; break;
            case 2: src = j * 65536 + i * 2048 + k * 64; break;
            case 3: src = k * 65536 + i * 2048 + j * 64; break;
            case 4: src = j * 65536 + k * 2048 + i * 64; break;
            default: src = k * 65536 + j * 2048 + i * 64; break;
        }
        float4 v = *(const float4*)(xb + src + c);
        ushort4 w;
        w.x = f2bf(v.x);
        w.y = f2bf(v.y);
        w.z = f2bf(v.z);
        w.w = f2bf(v.w);
        *(ushort4*)(&As[k * 392 + r]) = w;
    }
    __syncthreads();

    float4v acc0 = {0.f, 0.f, 0.f, 0.f};
    float4v acc1 = {0.f, 0.f, 0.f, 0.f};
    int mrow = m_tile * 16 + (lane & 15);
    const unsigned short* Arow = &As[mrow * 392 + (lane >> 4) * 8];
#pragma unroll
    for (int ks = 0; ks < 12; ++ks) {
        short8 a = *(const short8*)(Arow + ks * 32);
        acc0 = __builtin_amdgcn_mfma_f32_16x16x32_bf16(a, bfr[0][ks], acc0, 0, 0, 0);
        acc1 = __builtin_amdgcn_mfma_f32_16x16x32_bf16(a, bfr[1][ks], acc1, 0, 0, 0);
    }

    // epilogue: C/D layout col=lane&15, row=(lane>>4)*4+r
    float* Tb = T + (size_t)blk * 2048;
    int colq = lane & 15;
    int quad = lane >> 4;
#pragma unroll
    for (int np = 0; np < 2; ++np) {
        int o = (n_pair * 2 + np) * 16 + colq;
        float bb = b33[o];
        float4v acc = np ? acc1 : acc0;
#pragma unroll
        for (int r = 0; r < 4; ++r) {
            int m = m_tile * 16 + quad * 4 + r;
            Tb[m * 64 + o] = acc[r] + bb;
        }
    }
}

// ---------------------------------------------------------------------------
// K7: expand — scatter-add slices onto diagonal planes + mdiag on triple diag.
// ---------------------------------------------------------------------------
__global__ __launch_bounds__(256) void k_expand(float* __restrict__ T,
                                                const float* __restrict__ ws) {
    int id = blockIdx.x * 256 + threadIdx.x;  // 524288
    int o = id & 63;
    int d = (id >> 6) & 31;
    int t = (id >> 11) & 31;
    int b = id >> 16;
    size_t sb = (((size_t)b * 32 + t) * 32 + d) * 64 + o;
    float s0 = ws[OFF_SL + 0 * 524288 + sb];
    float s1 = ws[OFF_SL + 1 * 524288 + sb];
    float s2 = ws[OFF_SL + 2 * 524288 + sb];
    float* Tb = T + (size_t)b * 2097152;
    if (t != d) {
        Tb[d * 65536 + d * 2048 + t * 64 + o] += s0;
        Tb[d * 65536 + t * 2048 + d * 64 + o] += s1;
        Tb[t * 65536 + d * 2048 + d * 64 + o] += s2;
    } else {
        float md = ws[OFF_MD + ((size_t)b * 32 + d) * 64 + o];
        Tb[d * 65536 + d * 2048 + d * 64 + o] += s0 + s1 + s2 + md;
    }
}

// ---------------------------------------------------------------------------
extern "C" void kernel_launch(void* const* d_in, const int* in_sizes, int n_in,
                              void* d_out, int out_size, void* d_ws, size_t ws_size,
                              hipStream_t stream) {
    const float* x    = (const float*)d_in[0];
    const float* W33  = (const float*)d_in[1];
    const float* b33  = (const float*)d_in[2];
    const float* W22  = (const float*)d_in[3];
    const float* b22  = (const float*)d_in[4];
    const float* W12  = (const float*)d_in[5];
    const float* b12  = (const float*)d_in[6];
    const float* W12t = (const float*)d_in[7];
    const float* b12t = (const float*)d_in[8];
    const float* W02  = (const float*)d_in[9];
    const float* b02  = (const float*)d_in[10];
    const float* W11  = (const float*)d_in[11];
    const float* b11  = (const float*)d_in[12];
    const float* W01  = (const float*)d_in[13];
    const float* b01  = (const float*)d_in[14];
    float* T  = (float*)d_out;
    float* ws = (float*)d_ws;

    hipLaunchKernelGGL(k_prepw, dim3(12), dim3(256), 0, stream, W33, ws);
    hipLaunchKernelGGL(k_contract2, dim3(2048), dim3(256), 0, stream, x, ws);
    hipLaunchKernelGGL(k_contract1, dim3(64), dim3(256), 0, stream, x, ws);
    hipLaunchKernelGGL(k_contract0, dim3(2), dim3(256), 0, stream, ws);
    hipLaunchKernelGGL(k_rowmix, dim3(454), dim3(256), 0, stream,
                       W12, b12, W12t, b12t, W02, b02, W11, b11, W01, b01, ws);
    hipLaunchKernelGGL(k_slices, dim3(768), dim3(256), 0, stream, W22, b22, ws);
    hipLaunchKernelGGL(k_main, dim3(8192), dim3(256), 0, stream, x, ws, b33, T);
    hipLaunchKernelGGL(k_expand, dim3(2048), dim3(256), 0, stream, T, ws);
}

// Round 3
// 301.413 us; speedup vs baseline: 1.9492x; 1.1613x over previous
//
#include <hip/hip_runtime.h>

// SnConv3: B=8, N=32, C=64, O=64
#define NBATCH 8
#define NN 32
#define NC 64
#define NO 64
#define C6 384
#define C10 640
#define C12 768
#define C5 320

typedef __attribute__((ext_vector_type(8))) short short8;   // 8 bf16 (4 VGPRs)
typedef __attribute__((ext_vector_type(4))) float float4v;  // 4 fp32

// workspace layout (float offsets)
static constexpr int OFF_ABF = 0;        // a2 bf16 [8][32][32][384] = 1,572,864 floats
static constexpr int OFF_A1  = 1572864;  // [8][32][640] f32        =   163,840
static constexpr int OFF_A0  = 1736704;  // [8][320] f32            =     2,560
static constexpr int OFF_R1  = 1739264;  // [3][8][32][64]          =    49,152
static constexpr int OFF_R1T = 1788416;  // [3][8][32][64]          =    49,152
static constexpr int OFF_R0  = 1837568;  // [3][8][64]              =     1,536
static constexpr int OFF_MD  = 1839104;  // [8][32][64]             =    16,384
static constexpr int OFF_WB  = 1855488;  // W33 bf16 frags: 24576 sh =   12,288
static constexpr int OFF_WB2 = 1867776;  // W22 bf16 frags: 147456 sh=   73,728
// total 1,941,504 floats ~= 7.8 MB

__device__ __forceinline__ unsigned short f2bf(float f) {
    union { float f; unsigned u; } x{f};
    unsigned r = x.u + 0x7fffu + ((x.u >> 16) & 1u);  // RNE
    return (unsigned short)(r >> 16);
}

__device__ __forceinline__ void store_bf4(unsigned short* p, float4v v) {
    ushort4 w;
    w.x = f2bf(v.x); w.y = f2bf(v.y); w.z = f2bf(v.z); w.w = f2bf(v.w);
    *(ushort4*)p = w;
}

__device__ __forceinline__ float4v bf4(const unsigned short* p) {
    ushort4 u = *(const ushort4*)p;
    float4v r;
    r.x = __uint_as_float((unsigned)u.x << 16);
    r.y = __uint_as_float((unsigned)u.y << 16);
    r.z = __uint_as_float((unsigned)u.z << 16);
    r.w = __uint_as_float((unsigned)u.w << 16);
    return r;
}

// ---------------------------------------------------------------------------
// K0: weight prep. W33 [384][64] and W22 [3][768][64] f32 -> bf16 B-fragments
// for mfma_f32_16x16x32_bf16: lane l holds B[k0+j][n], k0=ks*32+(l>>4)*8, j=0..7
// ---------------------------------------------------------------------------
__global__ __launch_bounds__(256) void k_prepw(const float* __restrict__ W33,
                                               const float* __restrict__ W22,
                                               float* __restrict__ ws) {
    int id = blockIdx.x * 256 + threadIdx.x;  // 21504
    if (id < 3072) {                          // W33: nt(4) x ks(12) x lane(64)
        int lane = id & 63;
        int ks = (id >> 6) % 12;
        int nt = (id >> 6) / 12;
        int n = nt * 16 + (lane & 15);
        int k0 = ks * 32 + (lane >> 4) * 8;
        unsigned short* dst = (unsigned short*)(ws + OFF_WB) +
                              (size_t)((nt * 12 + ks) * 64 + lane) * 8;
#pragma unroll
        for (int jj = 0; jj < 8; ++jj) dst[jj] = f2bf(W33[(k0 + jj) * 64 + n]);
    } else if (id < 21504) {                  // W22: i(3) x nt(4) x ks(24) x lane(64)
        int q = id - 3072;
        int lane = q & 63;
        int ks = (q >> 6) % 24;
        int r = (q >> 6) / 24;
        int nt = r & 3;
        int i = r >> 2;
        int n = nt * 16 + (lane & 15);
        int k0 = ks * 32 + (lane >> 4) * 8;
        const float* W = W22 + (size_t)i * C12 * NO;
        unsigned short* dst = (unsigned short*)(ws + OFF_WB2) +
                              (size_t)(((i * 4 + nt) * 24 + ks) * 64 + lane) * 8;
#pragma unroll
        for (int jj = 0; jj < 8; ++jj) dst[jj] = f2bf(W[(k0 + jj) * 64 + n]);
    }
}

// ---------------------------------------------------------------------------
// K1: a2 (bf16): s1,s2,s3 (axis means) + d12,d13,d23 (diagonals)
// thread per (b,u,v,c4): 131072 threads, float4 loads
// ---------------------------------------------------------------------------
__global__ __launch_bounds__(256) void k_contract2(const float* __restrict__ x,
                                                   float* __restrict__ ws) {
    int id = blockIdx.x * 256 + threadIdx.x;
    int c4 = id & 15;
    int v = (id >> 4) & 31;
    int u = (id >> 9) & 31;
    int b = id >> 14;
    int bc = c4 * 4;
    const float* xb = x + (size_t)b * 2097152;

    float4v s1 = {0.f, 0.f, 0.f, 0.f}, s2 = s1, s3 = s1;
    {
        const float* p = xb + u * 2048 + v * 64 + bc;
        for (int i = 0; i < 32; ++i) s1 += *(const float4v*)(p + i * 65536);
    }
    {
        const float* p = xb + u * 65536 + v * 64 + bc;
        for (int j = 0; j < 32; ++j) s2 += *(const float4v*)(p + j * 2048);
    }
    {
        const float* p = xb + u * 65536 + v * 2048 + bc;
        for (int k = 0; k < 32; ++k) s3 += *(const float4v*)(p + k * 64);
    }
    float4v d12 = *(const float4v*)(xb + v * 65536 + v * 2048 + u * 64 + bc);
    float4v d13 = *(const float4v*)(xb + v * 65536 + u * 2048 + v * 64 + bc);
    float4v d23 = *(const float4v*)(xb + u * 65536 + v * 2048 + v * 64 + bc);

    const float inv = 1.0f / 32.0f;
    unsigned short* a2 = (unsigned short*)(ws + OFF_ABF) +
                         (size_t)((b * 32 + u) * 32 + v) * C6 + bc;
    store_bf4(a2 + 0 * 64, s1 * inv);
    store_bf4(a2 + 1 * 64, s2 * inv);
    store_bf4(a2 + 2 * 64, s3 * inv);
    store_bf4(a2 + 3 * 64, d12);
    store_bf4(a2 + 4 * 64, d13);
    store_bf4(a2 + 5 * 64, d23);
}

// ---------------------------------------------------------------------------
// K2: a1 (10 chunks of C, f32) from bf16 a2 + triple diagonal from x.
// thread per (b,t,c4): 4096 threads
// ---------------------------------------------------------------------------
__global__ __launch_bounds__(256) void k_contract1(const float* __restrict__ x,
                                                   float* __restrict__ ws) {
    int id = blockIdx.x * 256 + threadIdx.x;  // 4096
    int c4 = id & 15;
    int t = (id >> 4) & 31;
    int b = id >> 9;
    int bc = c4 * 4;
    const unsigned short* a2 = (const unsigned short*)(ws + OFF_ABF) +
                               (size_t)b * 32 * 32 * C6;

    float4v su0 = {0.f,0.f,0.f,0.f}, su3 = su0, su4 = su0, su5 = su0;
    float4v sv0 = su0, sv1 = su0, sv3 = su0, sv4 = su0, sv5 = su0;
    for (int u = 0; u < 32; ++u) {
        const unsigned short* row = a2 + (size_t)(u * 32 + t) * C6 + bc;
        su0 += bf4(row + 0);
        su3 += bf4(row + 192);
        su4 += bf4(row + 256);
        su5 += bf4(row + 320);
    }
    for (int v = 0; v < 32; ++v) {
        const unsigned short* row = a2 + (size_t)(t * 32 + v) * C6 + bc;
        sv0 += bf4(row + 0);
        sv1 += bf4(row + 64);
        sv3 += bf4(row + 192);
        sv4 += bf4(row + 256);
        sv5 += bf4(row + 320);
    }
    float4v td = *(const float4v*)(x + (((size_t)b * 32 + t) * 32 + t) * 2048 + t * 64 + bc);

    float* a1 = ws + OFF_A1 + ((size_t)b * 32 + t) * C10;
    const float inv = 1.0f / 32.0f;
    *(float4v*)(a1 + 0 * 64 + bc) = su0 * inv;
    *(float4v*)(a1 + 1 * 64 + bc) = sv0 * inv;
    *(float4v*)(a1 + 2 * 64 + bc) = sv1 * inv;
    *(float4v*)(a1 + 3 * 64 + bc) = su3 * inv;
    *(float4v*)(a1 + 4 * 64 + bc) = sv3 * inv;
    *(float4v*)(a1 + 5 * 64 + bc) = su4 * inv;
    *(float4v*)(a1 + 6 * 64 + bc) = sv4 * inv;
    *(float4v*)(a1 + 7 * 64 + bc) = su5 * inv;
    *(float4v*)(a1 + 8 * 64 + bc) = sv5 * inv;
    *(float4v*)(a1 + 9 * 64 + bc) = td;
}

// ---------------------------------------------------------------------------
// K3: a0 (5 chunks of C) from a1.
// ---------------------------------------------------------------------------
__global__ __launch_bounds__(256) void k_contract0(float* __restrict__ ws) {
    int id = blockIdx.x * 256 + threadIdx.x;
    if (id >= 512) return;
    int c = id & 63;
    int b = id >> 6;
    const float* a1 = ws + OFF_A1 + (size_t)b * 32 * C10;
    float s0 = 0, s1 = 0, s2 = 0, s3 = 0, s4 = 0;
    for (int t = 0; t < 32; ++t) {
        const float* row = a1 + t * C10;
        s0 += row[0 * 64 + c];
        s1 += row[3 * 64 + c];
        s2 += row[5 * 64 + c];
        s3 += row[7 * 64 + c];
        s4 += row[9 * 64 + c];
    }
    float* a0 = ws + OFF_A0 + b * C5;
    const float inv = 1.0f / 32.0f;
    a0[0 * 64 + c] = s0 * inv;
    a0[1 * 64 + c] = s1 * inv;
    a0[2 * 64 + c] = s2 * inv;
    a0[3 * 64 + c] = s3 * inv;
    a0[4 * 64 + c] = s4 * inv;
}

// ---------------------------------------------------------------------------
// K4: small row GEMMs: r1, r1t, mdiag, r0
// ---------------------------------------------------------------------------
__global__ __launch_bounds__(256) void k_rowmix(
    const float* __restrict__ W12, const float* __restrict__ b12,
    const float* __restrict__ W12t, const float* __restrict__ b12t,
    const float* __restrict__ W02, const float* __restrict__ b02,
    const float* __restrict__ W11, const float* __restrict__ b11,
    const float* __restrict__ W01, const float* __restrict__ b01,
    float* __restrict__ ws) {
    int id = blockIdx.x * 256 + threadIdx.x;
    if (id < 98304) {  // r1 / r1t
        bool second = id >= 49152;
        int q = second ? id - 49152 : id;
        int o = q & 63;
        int t = (q >> 6) & 31;
        int b = (q >> 11) & 7;
        int i = q >> 14;
        const float* W = (second ? W12t : W12) + (size_t)i * C10 * NO;
        const float* bb = (second ? b12t : b12) + i * NO;
        const float* a1 = ws + OFF_A1 + ((size_t)b * 32 + t) * C10;
        float acc = bb[o];
        for (int m = 0; m < C10; ++m) acc += a1[m] * W[m * NO + o];
        ws[(second ? OFF_R1T : OFF_R1) + (((size_t)i * 8 + b) * 32 + t) * NO + o] = acc;
    } else if (id < 114688) {  // mdiag
        int q = id - 98304;
        int o = q & 63;
        int t = (q >> 6) & 31;
        int b = q >> 11;
        const float* a1 = ws + OFF_A1 + ((size_t)b * 32 + t) * C10;
        const float* a0 = ws + OFF_A0 + (size_t)b * C5;
        float acc = b11[o] + b01[o];
        for (int m = 0; m < C10; ++m) acc += a1[m] * W11[m * NO + o];
        for (int m = 0; m < C5; ++m) acc += a0[m] * W01[m * NO + o];
        ws[OFF_MD + ((size_t)b * 32 + t) * NO + o] = acc;
    } else if (id < 116224) {  // r0
        int q = id - 114688;
        int o = q & 63;
        int b = (q >> 6) & 7;
        int i = q >> 9;
        const float* a0 = ws + OFF_A0 + (size_t)b * C5;
        float acc = b02[i * NO + o];
        for (int m = 0; m < C5; ++m) acc += a0[m] * W02[(size_t)i * C5 * NO + m * NO + o];
        ws[OFF_R0 + ((size_t)i * 8 + b) * NO + o] = acc;
    }
}

// ---------------------------------------------------------------------------
// K5 (main, MFMA): T[b,i,j,k,o] = b33[o] + sum_p,c x[b,perm_p(i,j,k),c]*W33[p*C+c,o]
// ---------------------------------------------------------------------------
__global__ __launch_bounds__(256) void k_main(const float* __restrict__ x,
                                              const float* __restrict__ ws,
                                              const float* __restrict__ b33,
                                              float* __restrict__ T) {
    __shared__ __align__(16) unsigned short As[32 * 392];  // 392 = 384 + 8 pad
    int blk = blockIdx.x;  // b*1024 + i*32 + j
    int b = blk >> 10;
    int i = (blk >> 5) & 31;
    int j = blk & 31;
    int tid = threadIdx.x;
    const float* xb = x + (size_t)b * 2097152;
    const unsigned short* WB = (const unsigned short*)(ws + OFF_WB);

    int wv = tid >> 6;
    int lane = tid & 63;
    int m_tile = wv & 1;
    int n_pair = wv >> 1;

    short8 bfr[2][12];
#pragma unroll
    for (int np = 0; np < 2; ++np) {
        int nt = n_pair * 2 + np;
#pragma unroll
        for (int ks = 0; ks < 12; ++ks)
            bfr[np][ks] = *(const short8*)(WB + (size_t)((nt * 12 + ks) * 64 + lane) * 8);
    }

    for (int l = tid; l < 3072; l += 256) {
        int f = l * 4;
        int k = f / C6;
        int r = f - k * C6;
        int p = r >> 6;
        int c = r & 63;
        int src;
        switch (p) {  // PERMS (1,2,3),(1,3,2),(2,1,3),(2,3,1),(3,1,2),(3,2,1)
            case 0: src = i * 65536 + j * 2048 + k * 64; break;
            case 1: src = i * 65536 + k * 2048 + j * 64; break;
            case 2: src = j * 65536 + i * 2048 + k * 64; break;
            case 3: src = k * 65536 + i * 2048 + j * 64; break;
            case 4: src = j * 65536 + k * 2048 + i * 64; break;
            default: src = k * 65536 + j * 2048 + i * 64; break;
        }
        float4v v = *(const float4v*)(xb + src + c);
        store_bf4(&As[k * 392 + r], v);
    }
    __syncthreads();

    float4v acc0 = {0.f, 0.f, 0.f, 0.f};
    float4v acc1 = {0.f, 0.f, 0.f, 0.f};
    int mrow = m_tile * 16 + (lane & 15);
    const unsigned short* Arow = &As[mrow * 392 + (lane >> 4) * 8];
#pragma unroll
    for (int ks = 0; ks < 12; ++ks) {
        short8 a = *(const short8*)(Arow + ks * 32);
        acc0 = __builtin_amdgcn_mfma_f32_16x16x32_bf16(a, bfr[0][ks], acc0, 0, 0, 0);
        acc1 = __builtin_amdgcn_mfma_f32_16x16x32_bf16(a, bfr[1][ks], acc1, 0, 0, 0);
    }

    float* Tb = T + (size_t)blk * 2048;
    int colq = lane & 15;
    int quad = lane >> 4;
#pragma unroll
    for (int np = 0; np < 2; ++np) {
        int o = (n_pair * 2 + np) * 16 + colq;
        float bb = b33[o];
        float4v acc = np ? acc1 : acc0;
#pragma unroll
        for (int r = 0; r < 4; ++r) {
            int m = m_tile * 16 + quad * 4 + r;
            Tb[m * 64 + o] = acc[r] + bb;
        }
    }
}

// ---------------------------------------------------------------------------
// K6 (slices, MFMA, fused expand): block per (b,t); A = [a2[b,t,d,:]|a2[b,d,t,:]]
// (32 x 768 bf16, rows padded +8); all 3 diagonal planes share the A-tile.
// Epilogue adds bias/r1/r1t/r0 (+mdiag on t==d) and RMWs T's diagonal planes
// directly. Cross-block collisions impossible (colliding triples => same thread).
// ---------------------------------------------------------------------------
__global__ __launch_bounds__(256) void k_slices(const float* __restrict__ b22,
                                                float* __restrict__ T,
                                                const float* __restrict__ ws) {
    __shared__ __align__(16) unsigned short As[32 * 776];  // 776 = 768 + 8 pad
    int blk = blockIdx.x;  // b*32 + t
    int b = blk >> 5;
    int t = blk & 31;
    int tid = threadIdx.x;
    const unsigned short* abf = (const unsigned short*)(ws + OFF_ABF);
    const unsigned short* WB2 = (const unsigned short*)(ws + OFF_WB2);

    for (int l = tid; l < 3072; l += 256) {  // 3072 chunks of 8 shorts
        int d = l / 96;
        int m8 = l - d * 96;
        const unsigned short* src = (m8 < 48)
            ? abf + (size_t)(((b * 32 + t) * 32 + d) * C6) + m8 * 8
            : abf + (size_t)(((b * 32 + d) * 32 + t) * C6) + (m8 - 48) * 8;
        *(short8*)&As[d * 776 + m8 * 8] = *(const short8*)src;
    }
    __syncthreads();

    int wv = tid >> 6;
    int lane = tid & 63;
    int mt = wv & 1;   // 16 d-rows
    int nh = wv >> 1;  // 2 n-tiles of 16 o's
    float4v zero = {0.f, 0.f, 0.f, 0.f};
    float4v acc[3][2] = {{zero, zero}, {zero, zero}, {zero, zero}};
    const unsigned short* Arow = &As[(mt * 16 + (lane & 15)) * 776 + (lane >> 4) * 8];
#pragma unroll
    for (int ks = 0; ks < 24; ++ks) {
        short8 a = *(const short8*)(Arow + ks * 32);
#pragma unroll
        for (int i = 0; i < 3; ++i) {
#pragma unroll
            for (int np = 0; np < 2; ++np) {
                int nt = nh * 2 + np;
                short8 bf = *(const short8*)(WB2 + (size_t)(((i * 4 + nt) * 24 + ks) * 64 + lane) * 8);
                acc[i][np] = __builtin_amdgcn_mfma_f32_16x16x32_bf16(a, bf, acc[i][np], 0, 0, 0);
            }
        }
    }

    int colq = lane & 15;
    int quad = lane >> 4;
    float* Tb = T + (size_t)b * 2097152;
#pragma unroll
    for (int np = 0; np < 2; ++np) {
        int o = (nh * 2 + np) * 16 + colq;
        float base0 = b22[0 * 64 + o] + ws[OFF_R1 + ((size_t)(0 * 8 + b) * 32 + t) * 64 + o]
                    + ws[OFF_R0 + (size_t)(0 * 8 + b) * 64 + o];
        float base1 = b22[1 * 64 + o] + ws[OFF_R1 + ((size_t)(1 * 8 + b) * 32 + t) * 64 + o]
                    + ws[OFF_R0 + (size_t)(1 * 8 + b) * 64 + o];
        float base2 = b22[2 * 64 + o] + ws[OFF_R1 + ((size_t)(2 * 8 + b) * 32 + t) * 64 + o]
                    + ws[OFF_R0 + (size_t)(2 * 8 + b) * 64 + o];
#pragma unroll
        for (int r = 0; r < 4; ++r) {
            int d = mt * 16 + quad * 4 + r;
            float s0 = acc[0][np][r] + base0 + ws[OFF_R1T + ((size_t)(0 * 8 + b) * 32 + d) * 64 + o];
            float s1 = acc[1][np][r] + base1 + ws[OFF_R1T + ((size_t)(1 * 8 + b) * 32 + d) * 64 + o];
            float s2 = acc[2][np][r] + base2 + ws[OFF_R1T + ((size_t)(2 * 8 + b) * 32 + d) * 64 + o];
            if (d != t) {
                Tb[d * 65536 + d * 2048 + t * 64 + o] += s0;  // plane (1,2)
                Tb[d * 65536 + t * 2048 + d * 64 + o] += s1;  // plane (1,3)
                Tb[t * 65536 + d * 2048 + d * 64 + o] += s2;  // plane (2,3)
            } else {
                float md = ws[OFF_MD + ((size_t)b * 32 + d) * 64 + o];
                Tb[d * 65536 + d * 2048 + d * 64 + o] += s0 + s1 + s2 + md;
            }
        }
    }
}

// ---------------------------------------------------------------------------
extern "C" void kernel_launch(void* const* d_in, const int* in_sizes, int n_in,
                              void* d_out, int out_size, void* d_ws, size_t ws_size,
                              hipStream_t stream) {
    const float* x    = (const float*)d_in[0];
    const float* W33  = (const float*)d_in[1];
    const float* b33  = (const float*)d_in[2];
    const float* W22  = (const float*)d_in[3];
    const float* b22  = (const float*)d_in[4];
    const float* W12  = (const float*)d_in[5];
    const float* b12  = (const float*)d_in[6];
    const float* W12t = (const float*)d_in[7];
    const float* b12t = (const float*)d_in[8];
    const float* W02  = (const float*)d_in[9];
    const float* b02  = (const float*)d_in[10];
    const float* W11  = (const float*)d_in[11];
    const float* b11  = (const float*)d_in[12];
    const float* W01  = (const float*)d_in[13];
    const float* b01  = (const float*)d_in[14];
    float* T  = (float*)d_out;
    float* ws = (float*)d_ws;

    hipLaunchKernelGGL(k_prepw, dim3(84), dim3(256), 0, stream, W33, W22, ws);
    hipLaunchKernelGGL(k_contract2, dim3(512), dim3(256), 0, stream, x, ws);
    hipLaunchKernelGGL(k_contract1, dim3(16), dim3(256), 0, stream, x, ws);
    hipLaunchKernelGGL(k_contract0, dim3(2), dim3(256), 0, stream, ws);
    hipLaunchKernelGGL(k_rowmix, dim3(454), dim3(256), 0, stream,
                       W12, b12, W12t, b12t, W02, b02, W11, b11, W01, b01, ws);
    hipLaunchKernelGGL(k_main, dim3(8192), dim3(256), 0, stream, x, ws, b33, T);
    hipLaunchKernelGGL(k_slices, dim3(256), dim3(256), 0, stream, b22, T, ws);
}

// Round 4
// 288.365 us; speedup vs baseline: 2.0374x; 1.0452x over previous
//
#include <hip/hip_runtime.h>

// SnConv3: B=8, N=32, C=64, O=64
#define NBATCH 8
#define NN 32
#define NC 64
#define NO 64
#define C6 384
#define C10 640
#define C12 768
#define C5 320

typedef __attribute__((ext_vector_type(8))) short short8;   // 8 bf16 (4 VGPRs)
typedef __attribute__((ext_vector_type(4))) float float4v;  // 4 fp32

// workspace layout (float offsets)
static constexpr int OFF_ABF = 0;        // a2 bf16 [8][32][32][384] = 1,572,864 floats
static constexpr int OFF_A1  = 1572864;  // [8][32][640] f32        =   163,840
static constexpr int OFF_A0  = 1736704;  // [8][320] f32            =     2,560
static constexpr int OFF_R1  = 1739264;  // [3][8][32][64]          =    49,152
static constexpr int OFF_R1T = 1788416;  // [3][8][32][64]          =    49,152
static constexpr int OFF_R0  = 1837568;  // [3][8][64]              =     1,536
static constexpr int OFF_MD  = 1839104;  // [8][32][64]             =    16,384
static constexpr int OFF_WB  = 1855488;  // W33 bf16 frags: 24576 sh =   12,288
static constexpr int OFF_WB2 = 1867776;  // W22 bf16 frags: 147456 sh=   73,728
// total 1,941,504 floats ~= 7.8 MB

__device__ __forceinline__ unsigned short f2bf(float f) {
    union { float f; unsigned u; } x{f};
    unsigned r = x.u + 0x7fffu + ((x.u >> 16) & 1u);  // RNE
    return (unsigned short)(r >> 16);
}

__device__ __forceinline__ void store_bf4(unsigned short* p, float4v v) {
    ushort4 w;
    w.x = f2bf(v.x); w.y = f2bf(v.y); w.z = f2bf(v.z); w.w = f2bf(v.w);
    *(ushort4*)p = w;
}

__device__ __forceinline__ float4v bf4(const unsigned short* p) {
    ushort4 u = *(const ushort4*)(p);
    float4v r;
    r.x = __uint_as_float((unsigned)u.x << 16);
    r.y = __uint_as_float((unsigned)u.y << 16);
    r.z = __uint_as_float((unsigned)u.z << 16);
    r.w = __uint_as_float((unsigned)u.w << 16);
    return r;
}

// ---------------------------------------------------------------------------
// K0: weight prep. W33 [384][64] and W22 [3][768][64] f32 -> bf16 B-fragments
// for mfma_f32_16x16x32_bf16: lane l holds B[k0+j][n], k0=ks*32+(l>>4)*8, j=0..7
// ---------------------------------------------------------------------------
__global__ __launch_bounds__(256) void k_prepw(const float* __restrict__ W33,
                                               const float* __restrict__ W22,
                                               float* __restrict__ ws) {
    int id = blockIdx.x * 256 + threadIdx.x;  // 21504
    if (id < 3072) {                          // W33: nt(4) x ks(12) x lane(64)
        int lane = id & 63;
        int ks = (id >> 6) % 12;
        int nt = (id >> 6) / 12;
        int n = nt * 16 + (lane & 15);
        int k0 = ks * 32 + (lane >> 4) * 8;
        unsigned short* dst = (unsigned short*)(ws + OFF_WB) +
                              (size_t)((nt * 12 + ks) * 64 + lane) * 8;
#pragma unroll
        for (int jj = 0; jj < 8; ++jj) dst[jj] = f2bf(W33[(k0 + jj) * 64 + n]);
    } else if (id < 21504) {                  // W22: i(3) x nt(4) x ks(24) x lane(64)
        int q = id - 3072;
        int lane = q & 63;
        int ks = (q >> 6) % 24;
        int r = (q >> 6) / 24;
        int nt = r & 3;
        int i = r >> 2;
        int n = nt * 16 + (lane & 15);
        int k0 = ks * 32 + (lane >> 4) * 8;
        const float* W = W22 + (size_t)i * C12 * NO;
        unsigned short* dst = (unsigned short*)(ws + OFF_WB2) +
                              (size_t)(((i * 4 + nt) * 24 + ks) * 64 + lane) * 8;
#pragma unroll
        for (int jj = 0; jj < 8; ++jj) dst[jj] = f2bf(W[(k0 + jj) * 64 + n]);
    }
}

// ---------------------------------------------------------------------------
// K1: a2 (bf16): s1,s2,s3 (axis means) + d12,d13,d23 (diagonals)
// thread per (b,u,v,c4): 131072 threads, float4 loads
// ---------------------------------------------------------------------------
__global__ __launch_bounds__(256) void k_contract2(const float* __restrict__ x,
                                                   float* __restrict__ ws) {
    int id = blockIdx.x * 256 + threadIdx.x;
    int c4 = id & 15;
    int v = (id >> 4) & 31;
    int u = (id >> 9) & 31;
    int b = id >> 14;
    int bc = c4 * 4;
    const float* xb = x + (size_t)b * 2097152;

    float4v s1 = {0.f, 0.f, 0.f, 0.f}, s2 = s1, s3 = s1;
    {
        const float* p = xb + u * 2048 + v * 64 + bc;
        for (int i = 0; i < 32; ++i) s1 += *(const float4v*)(p + i * 65536);
    }
    {
        const float* p = xb + u * 65536 + v * 64 + bc;
        for (int j = 0; j < 32; ++j) s2 += *(const float4v*)(p + j * 2048);
    }
    {
        const float* p = xb + u * 65536 + v * 2048 + bc;
        for (int k = 0; k < 32; ++k) s3 += *(const float4v*)(p + k * 64);
    }
    float4v d12 = *(const float4v*)(xb + v * 65536 + v * 2048 + u * 64 + bc);
    float4v d13 = *(const float4v*)(xb + v * 65536 + u * 2048 + v * 64 + bc);
    float4v d23 = *(const float4v*)(xb + u * 65536 + v * 2048 + v * 64 + bc);

    const float inv = 1.0f / 32.0f;
    unsigned short* a2 = (unsigned short*)(ws + OFF_ABF) +
                         (size_t)((b * 32 + u) * 32 + v) * C6 + bc;
    store_bf4(a2 + 0 * 64, s1 * inv);
    store_bf4(a2 + 1 * 64, s2 * inv);
    store_bf4(a2 + 2 * 64, s3 * inv);
    store_bf4(a2 + 3 * 64, d12);
    store_bf4(a2 + 4 * 64, d13);
    store_bf4(a2 + 5 * 64, d23);
}

// ---------------------------------------------------------------------------
// K2: a1 (10 chunks of C, f32) from bf16 a2 + triple diagonal from x.
// ---------------------------------------------------------------------------
__global__ __launch_bounds__(256) void k_contract1(const float* __restrict__ x,
                                                   float* __restrict__ ws) {
    int id = blockIdx.x * 256 + threadIdx.x;  // 4096
    int c4 = id & 15;
    int t = (id >> 4) & 31;
    int b = id >> 9;
    int bc = c4 * 4;
    const unsigned short* a2 = (const unsigned short*)(ws + OFF_ABF) +
                               (size_t)b * 32 * 32 * C6;

    float4v su0 = {0.f,0.f,0.f,0.f}, su3 = su0, su4 = su0, su5 = su0;
    float4v sv0 = su0, sv1 = su0, sv3 = su0, sv4 = su0, sv5 = su0;
    for (int u = 0; u < 32; ++u) {
        const unsigned short* row = a2 + (size_t)(u * 32 + t) * C6 + bc;
        su0 += bf4(row + 0);
        su3 += bf4(row + 192);
        su4 += bf4(row + 256);
        su5 += bf4(row + 320);
    }
    for (int v = 0; v < 32; ++v) {
        const unsigned short* row = a2 + (size_t)(t * 32 + v) * C6 + bc;
        sv0 += bf4(row + 0);
        sv1 += bf4(row + 64);
        sv3 += bf4(row + 192);
        sv4 += bf4(row + 256);
        sv5 += bf4(row + 320);
    }
    float4v td = *(const float4v*)(x + (((size_t)b * 32 + t) * 32 + t) * 2048 + t * 64 + bc);

    float* a1 = ws + OFF_A1 + ((size_t)b * 32 + t) * C10;
    const float inv = 1.0f / 32.0f;
    *(float4v*)(a1 + 0 * 64 + bc) = su0 * inv;
    *(float4v*)(a1 + 1 * 64 + bc) = sv0 * inv;
    *(float4v*)(a1 + 2 * 64 + bc) = sv1 * inv;
    *(float4v*)(a1 + 3 * 64 + bc) = su3 * inv;
    *(float4v*)(a1 + 4 * 64 + bc) = sv3 * inv;
    *(float4v*)(a1 + 5 * 64 + bc) = su4 * inv;
    *(float4v*)(a1 + 6 * 64 + bc) = sv4 * inv;
    *(float4v*)(a1 + 7 * 64 + bc) = su5 * inv;
    *(float4v*)(a1 + 8 * 64 + bc) = sv5 * inv;
    *(float4v*)(a1 + 9 * 64 + bc) = td;
}

// ---------------------------------------------------------------------------
// K3: a0 (5 chunks of C) from a1.
// ---------------------------------------------------------------------------
__global__ __launch_bounds__(256) void k_contract0(float* __restrict__ ws) {
    int id = blockIdx.x * 256 + threadIdx.x;
    if (id >= 512) return;
    int c = id & 63;
    int b = id >> 6;
    const float* a1 = ws + OFF_A1 + (size_t)b * 32 * C10;
    float s0 = 0, s1 = 0, s2 = 0, s3 = 0, s4 = 0;
    for (int t = 0; t < 32; ++t) {
        const float* row = a1 + t * C10;
        s0 += row[0 * 64 + c];
        s1 += row[3 * 64 + c];
        s2 += row[5 * 64 + c];
        s3 += row[7 * 64 + c];
        s4 += row[9 * 64 + c];
    }
    float* a0 = ws + OFF_A0 + b * C5;
    const float inv = 1.0f / 32.0f;
    a0[0 * 64 + c] = s0 * inv;
    a0[1 * 64 + c] = s1 * inv;
    a0[2 * 64 + c] = s2 * inv;
    a0[3 * 64 + c] = s3 * inv;
    a0[4 * 64 + c] = s4 * inv;
}

// ---------------------------------------------------------------------------
// K4: small row GEMMs: r1, r1t, mdiag, r0
// ---------------------------------------------------------------------------
__global__ __launch_bounds__(256) void k_rowmix(
    const float* __restrict__ W12, const float* __restrict__ b12,
    const float* __restrict__ W12t, const float* __restrict__ b12t,
    const float* __restrict__ W02, const float* __restrict__ b02,
    const float* __restrict__ W11, const float* __restrict__ b11,
    const float* __restrict__ W01, const float* __restrict__ b01,
    float* __restrict__ ws) {
    int id = blockIdx.x * 256 + threadIdx.x;
    if (id < 98304) {  // r1 / r1t
        bool second = id >= 49152;
        int q = second ? id - 49152 : id;
        int o = q & 63;
        int t = (q >> 6) & 31;
        int b = (q >> 11) & 7;
        int i = q >> 14;
        const float* W = (second ? W12t : W12) + (size_t)i * C10 * NO;
        const float* bb = (second ? b12t : b12) + i * NO;
        const float* a1 = ws + OFF_A1 + ((size_t)b * 32 + t) * C10;
        float acc = bb[o];
        for (int m = 0; m < C10; ++m) acc += a1[m] * W[m * NO + o];
        ws[(second ? OFF_R1T : OFF_R1) + (((size_t)i * 8 + b) * 32 + t) * NO + o] = acc;
    } else if (id < 114688) {  // mdiag
        int q = id - 98304;
        int o = q & 63;
        int t = (q >> 6) & 31;
        int b = q >> 11;
        const float* a1 = ws + OFF_A1 + ((size_t)b * 32 + t) * C10;
        const float* a0 = ws + OFF_A0 + (size_t)b * C5;
        float acc = b11[o] + b01[o];
        for (int m = 0; m < C10; ++m) acc += a1[m] * W11[m * NO + o];
        for (int m = 0; m < C5; ++m) acc += a0[m] * W01[m * NO + o];
        ws[OFF_MD + ((size_t)b * 32 + t) * NO + o] = acc;
    } else if (id < 116224) {  // r0
        int q = id - 114688;
        int o = q & 63;
        int b = (q >> 6) & 7;
        int i = q >> 9;
        const float* a0 = ws + OFF_A0 + (size_t)b * C5;
        float acc = b02[i * NO + o];
        for (int m = 0; m < C5; ++m) acc += a0[m] * W02[(size_t)i * C5 * NO + m * NO + o];
        ws[OFF_R0 + ((size_t)i * 8 + b) * NO + o] = acc;
    }
}

// ---------------------------------------------------------------------------
// K5 (main, MFMA): T[b,i,j,k,o] = b33[o] + sum_p,c x[b,perm_p(i,j,k),c]*W33[p*C+c,o]
// Persistent: 2048 blocks x 4 tiles. Staging: wave wv stages k-slab [8wv,8wv+8)
// for all 6 perms with p compile-time (wave-uniform, single coalesced load path).
// B-fragments loaded once per block. T stores nontemporal.
// ---------------------------------------------------------------------------
__global__ __launch_bounds__(256) void k_main(const float* __restrict__ x,
                                              const float* __restrict__ ws,
                                              const float* __restrict__ b33,
                                              float* __restrict__ T) {
    __shared__ __align__(16) unsigned short As[32 * 392];  // 392 = 384 + 8 pad
    int tid = threadIdx.x;
    const unsigned short* WB = (const unsigned short*)(ws + OFF_WB);

    int wv = tid >> 6;
    int lane = tid & 63;
    int m_tile = wv & 1;
    int n_pair = wv >> 1;
    int colq = lane & 15;
    int quad = lane >> 4;

    // B fragments once per block (L2-resident, coalesced dwordx4)
    short8 bfr[2][12];
#pragma unroll
    for (int np = 0; np < 2; ++np) {
        int nt = n_pair * 2 + np;
#pragma unroll
        for (int ks = 0; ks < 12; ++ks)
            bfr[np][ks] = *(const short8*)(WB + (size_t)((nt * 12 + ks) * 64 + lane) * 8);
    }
    float bb0 = b33[(n_pair * 2 + 0) * 16 + colq];
    float bb1 = b33[(n_pair * 2 + 1) * 16 + colq];

    int k0 = wv * 8;         // this wave's k-slab
    int c = colq * 4;        // channel offset (float4)
    int mrow = m_tile * 16 + colq;
    const unsigned short* Arow = &As[mrow * 392 + quad * 8];

    for (int tile = blockIdx.x; tile < 8192; tile += 2048) {
        int b = tile >> 10;
        int i = (tile >> 5) & 31;
        int j = tile & 31;
        const float* xb = x + (size_t)b * 2097152;

        // stage: all 6 perms, p compile-time constant (wave-uniform path)
#pragma unroll
        for (int half = 0; half < 2; ++half) {
            int k = k0 + quad + half * 4;
            float4v v0 = *(const float4v*)(xb + i * 65536 + j * 2048 + k * 64 + c);
            float4v v1 = *(const float4v*)(xb + i * 65536 + k * 2048 + j * 64 + c);
            float4v v2 = *(const float4v*)(xb + j * 65536 + i * 2048 + k * 64 + c);
            float4v v3 = *(const float4v*)(xb + k * 65536 + i * 2048 + j * 64 + c);
            float4v v4 = *(const float4v*)(xb + j * 65536 + k * 2048 + i * 64 + c);
            float4v v5 = *(const float4v*)(xb + k * 65536 + j * 2048 + i * 64 + c);
            unsigned short* dst = &As[k * 392 + c];
            store_bf4(dst + 0 * 64, v0);
            store_bf4(dst + 1 * 64, v1);
            store_bf4(dst + 2 * 64, v2);
            store_bf4(dst + 3 * 64, v3);
            store_bf4(dst + 4 * 64, v4);
            store_bf4(dst + 5 * 64, v5);
        }
        __syncthreads();

        float4v acc0 = {0.f, 0.f, 0.f, 0.f};
        float4v acc1 = {0.f, 0.f, 0.f, 0.f};
#pragma unroll
        for (int ks = 0; ks < 12; ++ks) {
            short8 a = *(const short8*)(Arow + ks * 32);
            acc0 = __builtin_amdgcn_mfma_f32_16x16x32_bf16(a, bfr[0][ks], acc0, 0, 0, 0);
            acc1 = __builtin_amdgcn_mfma_f32_16x16x32_bf16(a, bfr[1][ks], acc1, 0, 0, 0);
        }

        float* Tb = T + (size_t)tile * 2048;
#pragma unroll
        for (int r = 0; r < 4; ++r) {
            int m = m_tile * 16 + quad * 4 + r;
            int o0 = (n_pair * 2 + 0) * 16 + colq;
            int o1 = (n_pair * 2 + 1) * 16 + colq;
            __builtin_nontemporal_store(acc0[r] + bb0, &Tb[m * 64 + o0]);
            __builtin_nontemporal_store(acc1[r] + bb1, &Tb[m * 64 + o1]);
        }
        __syncthreads();  // protect As before next tile's staging
    }
}

// ---------------------------------------------------------------------------
// K6 (slices, MFMA, fused expand): block per (b,t); A = [a2[b,t,d,:]|a2[b,d,t,:]]
// (32 x 768 bf16, rows padded +8); all 3 diagonal planes share the A-tile.
// Epilogue adds bias/r1/r1t/r0 (+mdiag on t==d) and RMWs T's diagonal planes
// directly. Cross-block collisions impossible (colliding triples => same thread).
// ---------------------------------------------------------------------------
__global__ __launch_bounds__(256) void k_slices(const float* __restrict__ b22,
                                                float* __restrict__ T,
                                                const float* __restrict__ ws) {
    __shared__ __align__(16) unsigned short As[32 * 776];  // 776 = 768 + 8 pad
    int blk = blockIdx.x;  // b*32 + t
    int b = blk >> 5;
    int t = blk & 31;
    int tid = threadIdx.x;
    const unsigned short* abf = (const unsigned short*)(ws + OFF_ABF);
    const unsigned short* WB2 = (const unsigned short*)(ws + OFF_WB2);

    for (int l = tid; l < 3072; l += 256) {  // 3072 chunks of 8 shorts
        int d = l / 96;
        int m8 = l - d * 96;
        const unsigned short* src = (m8 < 48)
            ? abf + (size_t)(((b * 32 + t) * 32 + d) * C6) + m8 * 8
            : abf + (size_t)(((b * 32 + d) * 32 + t) * C6) + (m8 - 48) * 8;
        *(short8*)&As[d * 776 + m8 * 8] = *(const short8*)src;
    }
    __syncthreads();

    int wv = tid >> 6;
    int lane = tid & 63;
    int mt = wv & 1;   // 16 d-rows
    int nh = wv >> 1;  // 2 n-tiles of 16 o's
    float4v zero = {0.f, 0.f, 0.f, 0.f};
    float4v acc[3][2] = {{zero, zero}, {zero, zero}, {zero, zero}};
    const unsigned short* Arow = &As[(mt * 16 + (lane & 15)) * 776 + (lane >> 4) * 8];
#pragma unroll
    for (int ks = 0; ks < 24; ++ks) {
        short8 a = *(const short8*)(Arow + ks * 32);
#pragma unroll
        for (int i = 0; i < 3; ++i) {
#pragma unroll
            for (int np = 0; np < 2; ++np) {
                int nt = nh * 2 + np;
                short8 bf = *(const short8*)(WB2 + (size_t)(((i * 4 + nt) * 24 + ks) * 64 + lane) * 8);
                acc[i][np] = __builtin_amdgcn_mfma_f32_16x16x32_bf16(a, bf, acc[i][np], 0, 0, 0);
            }
        }
    }

    int colq = lane & 15;
    int quad = lane >> 4;
    float* Tb = T + (size_t)b * 2097152;
#pragma unroll
    for (int np = 0; np < 2; ++np) {
        int o = (nh * 2 + np) * 16 + colq;
        float base0 = b22[0 * 64 + o] + ws[OFF_R1 + ((size_t)(0 * 8 + b) * 32 + t) * 64 + o]
                    + ws[OFF_R0 + (size_t)(0 * 8 + b) * 64 + o];
        float base1 = b22[1 * 64 + o] + ws[OFF_R1 + ((size_t)(1 * 8 + b) * 32 + t) * 64 + o]
                    + ws[OFF_R0 + (size_t)(1 * 8 + b) * 64 + o];
        float base2 = b22[2 * 64 + o] + ws[OFF_R1 + ((size_t)(2 * 8 + b) * 32 + t) * 64 + o]
                    + ws[OFF_R0 + (size_t)(2 * 8 + b) * 64 + o];
#pragma unroll
        for (int r = 0; r < 4; ++r) {
            int d = mt * 16 + quad * 4 + r;
            float s0 = acc[0][np][r] + base0 + ws[OFF_R1T + ((size_t)(0 * 8 + b) * 32 + d) * 64 + o];
            float s1 = acc[1][np][r] + base1 + ws[OFF_R1T + ((size_t)(1 * 8 + b) * 32 + d) * 64 + o];
            float s2 = acc[2][np][r] + base2 + ws[OFF_R1T + ((size_t)(2 * 8 + b) * 32 + d) * 64 + o];
            if (d != t) {
                Tb[d * 65536 + d * 2048 + t * 64 + o] += s0;  // plane (1,2)
                Tb[d * 65536 + t * 2048 + d * 64 + o] += s1;  // plane (1,3)
                Tb[t * 65536 + d * 2048 + d * 64 + o] += s2;  // plane (2,3)
            } else {
                float md = ws[OFF_MD + ((size_t)b * 32 + d) * 64 + o];
                Tb[d * 65536 + d * 2048 + d * 64 + o] += s0 + s1 + s2 + md;
            }
        }
    }
}

// ---------------------------------------------------------------------------
extern "C" void kernel_launch(void* const* d_in, const int* in_sizes, int n_in,
                              void* d_out, int out_size, void* d_ws, size_t ws_size,
                              hipStream_t stream) {
    const float* x    = (const float*)d_in[0];
    const float* W33  = (const float*)d_in[1];
    const float* b33  = (const float*)d_in[2];
    const float* W22  = (const float*)d_in[3];
    const float* b22  = (const float*)d_in[4];
    const float* W12  = (const float*)d_in[5];
    const float* b12  = (const float*)d_in[6];
    const float* W12t = (const float*)d_in[7];
    const float* b12t = (const float*)d_in[8];
    const float* W02  = (const float*)d_in[9];
    const float* b02  = (const float*)d_in[10];
    const float* W11  = (const float*)d_in[11];
    const float* b11  = (const float*)d_in[12];
    const float* W01  = (const float*)d_in[13];
    const float* b01  = (const float*)d_in[14];
    float* T  = (float*)d_out;
    float* ws = (float*)d_ws;

    hipLaunchKernelGGL(k_prepw, dim3(84), dim3(256), 0, stream, W33, W22, ws);
    hipLaunchKernelGGL(k_contract2, dim3(512), dim3(256), 0, stream, x, ws);
    hipLaunchKernelGGL(k_contract1, dim3(16), dim3(256), 0, stream, x, ws);
    hipLaunchKernelGGL(k_contract0, dim3(2), dim3(256), 0, stream, ws);
    hipLaunchKernelGGL(k_rowmix, dim3(454), dim3(256), 0, stream,
                       W12, b12, W12t, b12t, W02, b02, W11, b11, W01, b01, ws);
    hipLaunchKernelGGL(k_main, dim3(2048), dim3(256), 0, stream, x, ws, b33, T);
    hipLaunchKernelGGL(k_slices, dim3(256), dim3(256), 0, stream, b22, T, ws);
}